// Round 14
// baseline (320.309 us; speedup 1.0000x reference)
//
#include <hip/hip_runtime.h>

// AdaptiveGraphConvolution on MI355X (gfx950)
// out = sum_l m_l * (A_l @ x) @ W_l + bias
//
// R14: ONE fused gather+MFMA dispatch. MFMA acc registers carry the full
// K=128 x 4-graph sum (16 MFMAs/wave over (q,l)), so out is written exactly
// once, bias folded -- the 4-pass out RMW (~154MB HBM) is gone. Block's 4
// bucket edge lists staged in LDS once (cv reads 51->12.8MB); tile
// double-buffered (1 barrier per (q,l) phase). Build pipeline = R13.

constexpr int N = 50000;
constexpr int E = 800000;
constexpr int D = 128;
constexpr int L = 4;
constexpr int BSH = 4;            // 16 rows per bucket
constexpr int NB = N >> BSH;      // 3125 buckets
constexpr int NCHK = 100;
constexpr int CHUNK = E / NCHK;   // 8000
constexpr int CAP = 1024;         // max bucket size (mean 256, +48 sigma)

typedef __attribute__((ext_vector_type(8))) short bf16x8;
typedef __attribute__((ext_vector_type(4))) float f32x4;
union U4B8 { uint4 u; bf16x8 b; };

__device__ inline unsigned bf16rne(unsigned u) {
    return (u + 0x7FFFu + ((u >> 16) & 1u)) >> 16;
}

// ---------------------------------------------------------------------------
// 0a) x -> 4 feature-sliced bf16 tables xb[q][row][fl].
// ---------------------------------------------------------------------------
__global__ __launch_bounds__(256) void cvt_x_kernel(
    const float* __restrict__ x, unsigned* __restrict__ xb)
{
    int i = blockIdx.x * 256 + threadIdx.x;     // 0 .. N*64
    int row = i >> 6, j = i & 63;
    int q = j >> 4, fl = j & 15;
    float2 v = *reinterpret_cast<const float2*>(x + (size_t)row * D + q * 32 + fl * 2);
    xb[((size_t)q * N + row) * 16 + fl] =
        bf16rne(__float_as_uint(v.x)) | (bf16rne(__float_as_uint(v.y)) << 16);
}

// ---------------------------------------------------------------------------
// 0b) W -> transposed, mix-scaled bf16: WbT[l][f][dpair].
// ---------------------------------------------------------------------------
__global__ __launch_bounds__(256) void cvt_w_kernel(
    const float* __restrict__ W, const float* __restrict__ mix,
    unsigned* __restrict__ WbT)
{
    int idx = blockIdx.x * 256 + threadIdx.x;   // 0 .. L*64*128
    int f = idx & 127, dp = (idx >> 7) & 63, l = idx >> 13;
    float m = mix[l];
    float a = m * W[((size_t)l * D + 2 * dp) * D + f];
    float b = m * W[((size_t)l * D + 2 * dp + 1) * D + f];
    WbT[((size_t)l * D + f) * 64 + dp] =
        bf16rne(__float_as_uint(a)) | (bf16rne(__float_as_uint(b)) << 16);
}

// ---------------------------------------------------------------------------
// 1a) hist, grid (NCHK, L): LDS hist -> pcnt counts + chunk-local prefix.
// ---------------------------------------------------------------------------
__global__ __launch_bounds__(256) void hist_kernel(
    const int* __restrict__ edge_rows,
    unsigned short* __restrict__ pcnt,
    unsigned short* __restrict__ chunkoff)
{
    __shared__ int cnt[NB];
    __shared__ int psum[256];
    const int blk = blockIdx.x, g = blockIdx.y, tid = threadIdx.x;

    for (int i = tid; i < NB; i += 256) cnt[i] = 0;
    __syncthreads();

    const int* rows = edge_rows + (size_t)g * E + (size_t)blk * CHUNK;
    for (int i = tid; i < CHUNK; i += 256)
        atomicAdd(&cnt[rows[i] >> BSH], 1);
    __syncthreads();

    unsigned short* pc = pcnt + ((size_t)g * NCHK + blk) * NB;
    for (int i = tid; i < NB; i += 256) pc[i] = (unsigned short)cnt[i];
    __syncthreads();

    constexpr int CB = (NB + 255) / 256;   // 13
    const int base = tid * CB;
    int s = 0;
#pragma unroll
    for (int j = 0; j < CB; ++j) {
        int idx = base + j;
        if (idx < NB) s += cnt[idx];
    }
    psum[tid] = s;
    __syncthreads();
    for (int off = 1; off < 256; off <<= 1) {
        int v = (tid >= off) ? psum[tid - off] : 0;
        __syncthreads();
        psum[tid] += v;
        __syncthreads();
    }
    int carry = (tid == 0) ? 0 : psum[tid - 1];
#pragma unroll
    for (int j = 0; j < CB; ++j) {
        int idx = base + j;
        if (idx < NB) {
            int c = cnt[idx];
            cnt[idx] = carry;
            carry += c;
        }
    }
    __syncthreads();

    unsigned short* co = chunkoff + ((size_t)g * NCHK + blk) * NB;
    for (int i = tid; i < NB; i += 256) co[i] = (unsigned short)cnt[i];
}

// ---------------------------------------------------------------------------
// 1b) scatter, grid (NCHK, L): packed-u16 cursors; rank-scatter {cv, rl}
//     into LDS; coalesced copy-out.
// ---------------------------------------------------------------------------
__global__ __launch_bounds__(256) void scatter_kernel(
    const int* __restrict__ edge_rows,
    const int* __restrict__ edge_cols,
    const float* __restrict__ edge_vals,
    const unsigned short* __restrict__ chunkoff,
    unsigned* __restrict__ cvT,
    unsigned char* __restrict__ rlT)
{
    __shared__ unsigned cur[(NB + 1) / 2];
    __shared__ unsigned lcv[CHUNK];
    __shared__ unsigned char lrl[CHUNK];
    const int blk = blockIdx.x, g = blockIdx.y, tid = threadIdx.x;

    const unsigned short* co = chunkoff + ((size_t)g * NCHK + blk) * NB;
    for (int i = tid; i < (NB + 1) / 2; i += 256) {
        unsigned lo = co[2 * i];
        unsigned hi = (2 * i + 1 < NB) ? co[2 * i + 1] : 0u;
        cur[i] = lo | (hi << 16);
    }
    __syncthreads();

    const size_t eoff = (size_t)g * E + (size_t)blk * CHUNK;
    const int* rows = edge_rows + eoff;
    const int* cols = edge_cols + eoff;
    const float* vals = edge_vals + eoff;

    for (int i = tid; i < CHUNK; i += 256) {
        int r = rows[i];
        int b = r >> BSH;
        unsigned old = atomicAdd(&cur[b >> 1], (b & 1) ? 0x10000u : 1u);
        int pos = (old >> ((b & 1) * 16)) & 0xFFFFu;
        lcv[pos] = (unsigned)cols[i] | (bf16rne(__float_as_uint(vals[i])) << 16);
        lrl[pos] = (unsigned char)(r & 15);
    }
    __syncthreads();

    unsigned* cw = cvT + eoff;
    unsigned char* rw = rlT + eoff;
    for (int i = tid; i < CHUNK; i += 256) cw[i] = lcv[i];
    for (int i = tid * 4; i < CHUNK; i += 1024)
        *reinterpret_cast<uint*>(rw + i) = *reinterpret_cast<const uint*>(lrl + i);
}

// ---------------------------------------------------------------------------
// 2a) Column pass: pcnt counts -> cross-chunk offsets; totals -> bstart.
// ---------------------------------------------------------------------------
__global__ __launch_bounds__(256) void scan1_kernel(
    unsigned short* __restrict__ pcnt, int* __restrict__ bstart)
{
    const int b = blockIdx.x * 256 + threadIdx.x;
    const int g = blockIdx.y;
    if (b >= NB) return;
    unsigned run = 0;
    unsigned short* p = pcnt + (size_t)g * NCHK * NB + b;
    for (int blk = 0; blk < NCHK; ++blk) {
        unsigned v = p[(size_t)blk * NB];
        p[(size_t)blk * NB] = (unsigned short)run;
        run += v;
    }
    bstart[(size_t)g * (NB + 1) + b] = (int)run;
}

// ---------------------------------------------------------------------------
// 2b) Per-graph exclusive scan of bucket totals.
// ---------------------------------------------------------------------------
__global__ __launch_bounds__(1024) void scan2_kernel(int* __restrict__ bstart)
{
    __shared__ int sums[1024];
    int* bs = bstart + (size_t)blockIdx.x * (NB + 1);
    const int t = threadIdx.x;
    int tv[4];
    int s = 0;
#pragma unroll
    for (int i = 0; i < 4; ++i) {
        int idx = t * 4 + i;
        tv[i] = (idx < NB) ? bs[idx] : 0;
        s += tv[i];
    }
    sums[t] = s;
    __syncthreads();
    for (int off = 1; off < 1024; off <<= 1) {
        int v = (t >= off) ? sums[t - off] : 0;
        __syncthreads();
        sums[t] += v;
        __syncthreads();
    }
    int ex = (t == 0) ? 0 : sums[t - 1];
#pragma unroll
    for (int i = 0; i < 4; ++i) {
        int idx = t * 4 + i;
        if (idx < NB) { bs[idx] = ex; ex += tv[i]; }
    }
    if (t == 0) bs[NB] = E;
}

// ---------------------------------------------------------------------------
// 3) sort2 (pull payload), grid (NB, L): unchanged from R13.
// ---------------------------------------------------------------------------
__global__ __launch_bounds__(256) void sort2_kernel(
    const unsigned* __restrict__ cvT,
    const unsigned char* __restrict__ rlT,
    const unsigned short* __restrict__ pcnt,
    const unsigned short* __restrict__ chunkoff,
    const int* __restrict__ bstart,
    unsigned* __restrict__ cv,
    int* __restrict__ rowptr)
{
    __shared__ unsigned su_cv[CAP], ss_cv[CAP];
    __shared__ unsigned char su_rl[CAP];
    __shared__ int rc[17], rcur[16];
    const int b = blockIdx.x, g = blockIdx.y, tid = threadIdx.x;
    const int beg = bstart[(size_t)g * (NB + 1) + b];
    const int tot = bstart[(size_t)g * (NB + 1) + b + 1] - beg;
    const int cnt = tot < CAP ? tot : CAP;
    int* rp = rowptr + (size_t)g * (N + 1);
    if (b == 0 && tid == 0) rp[N] = E;
    if (tid < 17) rc[tid] = 0;

    if (tid < NCHK) {
        const int c = tid;
        const size_t pbase = ((size_t)g * NCHK + c) * NB + b;
        int off = pcnt[pbase];
        int nxt = (c == NCHK - 1) ? tot : (int)pcnt[pbase + NB];
        int len = nxt - off;
        const size_t wbase = (size_t)g * E + (size_t)c * CHUNK + chunkoff[pbase];
        const unsigned* cw = cvT + wbase;
        const unsigned char* rw = rlT + wbase;
        for (int i = 0; i < len; ++i) {
            int p = off + i;
            if (p < CAP) { su_cv[p] = cw[i]; su_rl[p] = rw[i]; }
        }
    }
    __syncthreads();

    for (int i = tid; i < cnt; i += 256) atomicAdd(&rc[su_rl[i] + 1], 1);
    __syncthreads();
    if (tid == 0) {
        int run = 0;
#pragma unroll
        for (int r = 1; r <= 16; ++r) { run += rc[r]; rc[r] = run; }
    }
    __syncthreads();
    if (tid < 16) {
        rcur[tid] = rc[tid];
        rp[b * 16 + tid] = beg + rc[tid];
    }
    __syncthreads();
    for (int i = tid; i < cnt; i += 256) {
        int p = atomicAdd(&rcur[su_rl[i]], 1);
        ss_cv[p] = su_cv[i];
    }
    __syncthreads();
    unsigned* cvg = cv + (size_t)g * E;
    for (int i = tid; i < cnt; i += 256) cvg[beg + i] = ss_cv[i];
}

// ---------------------------------------------------------------------------
// 4) fused_all, grid N/16: ONE dispatch. Stage the block's 4 bucket edge
//    lists in LDS (16KB cap) + per-row local offsets. Then for q, for l:
//    subs gather rows (R13 MLP body, cvr from LDS) -> bf16 tile (double-
//    buffered, 1 barrier/phase) -> 2 MFMAs/wave accumulating over ALL
//    (q,l) in registers. One out write with bias at the end.
// ---------------------------------------------------------------------------
__global__ __launch_bounds__(256) void fused_all_kernel(
    const unsigned* __restrict__ xb,      // [4][N][16]
    const unsigned* __restrict__ cv,      // [L][E]
    const int* __restrict__ rowptr,       // [L][N+1]
    const int* __restrict__ bstart,       // [L][NB+1]
    const unsigned* __restrict__ WbT,     // [L][128][64] bf16 pairs (scaled)
    const float* __restrict__ bias,
    float* __restrict__ out)
{
    __shared__ unsigned scv[L][CAP];          // 16 KB staged edge payloads
    __shared__ unsigned short rloc[L][17];    // per-row local offsets
    __shared__ unsigned tile[2][16][16];      // 2 KB double-buffered A tile

    const int b = blockIdx.x;
    const int tid = threadIdx.x;
    const int lane = tid & 63;
    const int wave = tid >> 6;
    const int sub = lane >> 4;
    const int fl = lane & 15;
    const int subbase = lane & 48;
    const int trow = wave * 4 + sub;
    const int lrow = lane & 15, kgrp = lane >> 4;

    // stage: 4 bucket edge lists + row-local offsets
    for (int l = 0; l < L; ++l) {
        const int beg = bstart[l * (NB + 1) + b];
        int cnt = bstart[l * (NB + 1) + b + 1] - beg;
        if (cnt > CAP) cnt = CAP;
        const unsigned* src = cv + (size_t)l * E + beg;
        for (int i = tid; i < cnt; i += 256) scv[l][i] = src[i];
        if (tid < 17) {
            int v = rowptr[l * (N + 1) + b * 16 + tid] - beg;
            rloc[l][tid] = (unsigned short)(v > CAP ? CAP : v);
        }
    }
    __syncthreads();

    f32x4 acc[2] = {};
    int tb = 0;

    for (int q = 0; q < 4; ++q) {
        const unsigned* xq = xb + (size_t)q * N * 16;
        for (int l = 0; l < L; ++l) {
            const int s0 = rloc[l][trow], s1 = rloc[l][trow + 1];
            float accx = 0.f, accy = 0.f;
            for (int base = s0; base < s1; base += 16) {
                const int cnt = s1 - base;
                unsigned cvr = (fl < cnt) ? scv[l][base + fl] : 0u;
#pragma unroll
                for (int k = 0; k < 16; k += 4) {
                    unsigned c0 = __shfl(cvr, subbase + k + 0);
                    unsigned c1 = __shfl(cvr, subbase + k + 1);
                    unsigned c2 = __shfl(cvr, subbase + k + 2);
                    unsigned c3 = __shfl(cvr, subbase + k + 3);
                    unsigned x0 = xq[(size_t)(c0 & 0xFFFFu) * 16 + fl];
                    unsigned x1 = xq[(size_t)(c1 & 0xFFFFu) * 16 + fl];
                    unsigned x2 = xq[(size_t)(c2 & 0xFFFFu) * 16 + fl];
                    unsigned x3 = xq[(size_t)(c3 & 0xFFFFu) * 16 + fl];
                    float v0 = __uint_as_float(c0 & 0xFFFF0000u);  // pad -> +0
                    float v1 = __uint_as_float(c1 & 0xFFFF0000u);
                    float v2 = __uint_as_float(c2 & 0xFFFF0000u);
                    float v3 = __uint_as_float(c3 & 0xFFFF0000u);
                    accx = fmaf(v0, __uint_as_float(x0 << 16), accx);
                    accy = fmaf(v0, __uint_as_float(x0 & 0xFFFF0000u), accy);
                    accx = fmaf(v1, __uint_as_float(x1 << 16), accx);
                    accy = fmaf(v1, __uint_as_float(x1 & 0xFFFF0000u), accy);
                    accx = fmaf(v2, __uint_as_float(x2 << 16), accx);
                    accy = fmaf(v2, __uint_as_float(x2 & 0xFFFF0000u), accy);
                    accx = fmaf(v3, __uint_as_float(x3 << 16), accx);
                    accy = fmaf(v3, __uint_as_float(x3 & 0xFFFF0000u), accy);
                }
            }
            tile[tb][trow][fl] = bf16rne(__float_as_uint(accx)) |
                                 (bf16rne(__float_as_uint(accy)) << 16);
            __syncthreads();   // tile[tb] writes visible; prior reads of
                               // tile[tb^1] completed before this barrier

            U4B8 a;
            a.u = *reinterpret_cast<const uint4*>(&tile[tb][lrow][kgrp * 4]);
#pragma unroll
            for (int t = 0; t < 2; ++t) {
                const int f = wave * 32 + t * 16 + lrow;
                U4B8 bb;
                bb.u = *reinterpret_cast<const uint4*>(
                    WbT + ((size_t)l * D + f) * 64 + q * 16 + kgrp * 4);
                acc[t] = __builtin_amdgcn_mfma_f32_16x16x32_bf16(
                    a.b, bb.b, acc[t], 0, 0, 0);
            }
            tb ^= 1;   // next phase writes the other buffer
        }
    }

#pragma unroll
    for (int t = 0; t < 2; ++t) {
        const int f = wave * 32 + t * 16 + lrow;
        const float bv = bias[f];
#pragma unroll
        for (int i = 0; i < 4; ++i) {
            int orow = b * 16 + kgrp * 4 + i;
            out[(size_t)orow * D + f] = acc[t][i] + bv;
        }
    }
}

extern "C" void kernel_launch(void* const* d_in, const int* in_sizes, int n_in,
                              void* d_out, int out_size, void* d_ws, size_t ws_size,
                              hipStream_t stream)
{
    const float* x         = (const float*)d_in[0];
    const int*   edge_rows = (const int*)d_in[1];
    const int*   edge_cols = (const int*)d_in[2];
    const float* edge_vals = (const float*)d_in[3];
    const float* W         = (const float*)d_in[4];
    const float* mix       = (const float*)d_in[5];
    const float* bias      = (const float*)d_in[6];
    float* out = (float*)d_out;

    // Workspace (~47.6 MB), layout as R13:
    // cvT [L][E] u32 (12.8M) | rlT [L][E] u8 (3.2M) | pcnt u16 (2.5M) |
    // chunkoff u16 (2.5M) | bstart (50K) | rowptr (0.8M) | cv [L][E] (12.8M) |
    // xb [4][N][16] (12.8M) | WbT (128K)
    unsigned*       cvT      = (unsigned*)d_ws;
    unsigned char*  rlT      = (unsigned char*)(cvT + (size_t)L * E);
    unsigned short* pcnt     = (unsigned short*)(rlT + (size_t)L * E);
    unsigned short* chunkoff = pcnt + (size_t)L * NCHK * NB;
    int*            bstart   = (int*)(chunkoff + (size_t)L * NCHK * NB);
    int*            rowptr   = bstart + (size_t)L * (NB + 1);
    unsigned*       cv       = (unsigned*)(rowptr + (size_t)L * (N + 1));
    unsigned*       xb       = cv + (size_t)L * E;
    unsigned*       WbT      = xb + (size_t)4 * N * 16;

    cvt_x_kernel<<<(N * 64) / 256, 256, 0, stream>>>(x, xb);
    cvt_w_kernel<<<(L * D * 64) / 256, 256, 0, stream>>>(W, mix, WbT);
    hist_kernel<<<dim3(NCHK, L), 256, 0, stream>>>(edge_rows, pcnt, chunkoff);
    scatter_kernel<<<dim3(NCHK, L), 256, 0, stream>>>(edge_rows, edge_cols,
                                                      edge_vals, chunkoff, cvT, rlT);
    scan1_kernel<<<dim3((NB + 255) / 256, L), 256, 0, stream>>>(pcnt, bstart);
    scan2_kernel<<<L, 1024, 0, stream>>>(bstart);
    sort2_kernel<<<dim3(NB, L), 256, 0, stream>>>(cvT, rlT, pcnt, chunkoff, bstart,
                                                  cv, rowptr);

    fused_all_kernel<<<N / 16, 256, 0, stream>>>(xb, cv, rowptr, bstart,
                                                 WbT, bias, out);
}

// Round 15
// 301.338 us; speedup vs baseline: 1.0630x; 1.0630x over previous
//
#include <hip/hip_runtime.h>

// AdaptiveGraphConvolution on MI355X (gfx950)
// out = sum_l m_l * (A_l @ x) @ W_l + bias
//
// R15: back to R13's 4 phase-synced sliced fused dispatches (R14's in-kernel
// q-loop broke slice residency: FETCH 165->585MB, L3-bound). Fused kernel
// tightened: (1) 4-slot unrolled inner groups cut Poisson-padding 53%->12%
// (16-wide coalesced cv batch load kept); (2) double-buffered A tile halves
// barriers (R14-validated pattern). Build pipeline unchanged from R13.

constexpr int N = 50000;
constexpr int E = 800000;
constexpr int D = 128;
constexpr int L = 4;
constexpr int BSH = 4;            // 16 rows per bucket
constexpr int NB = N >> BSH;      // 3125 buckets
constexpr int NCHK = 100;
constexpr int CHUNK = E / NCHK;   // 8000
constexpr int CAP = 1024;         // max bucket size (mean 256, +48 sigma)

typedef __attribute__((ext_vector_type(8))) short bf16x8;
typedef __attribute__((ext_vector_type(4))) float f32x4;
union U4B8 { uint4 u; bf16x8 b; };

__device__ inline unsigned bf16rne(unsigned u) {
    return (u + 0x7FFFu + ((u >> 16) & 1u)) >> 16;
}

// ---------------------------------------------------------------------------
// 0a) x -> 4 feature-sliced bf16 tables xb[q][row][fl].
// ---------------------------------------------------------------------------
__global__ __launch_bounds__(256) void cvt_x_kernel(
    const float* __restrict__ x, unsigned* __restrict__ xb)
{
    int i = blockIdx.x * 256 + threadIdx.x;     // 0 .. N*64
    int row = i >> 6, j = i & 63;
    int q = j >> 4, fl = j & 15;
    float2 v = *reinterpret_cast<const float2*>(x + (size_t)row * D + q * 32 + fl * 2);
    xb[((size_t)q * N + row) * 16 + fl] =
        bf16rne(__float_as_uint(v.x)) | (bf16rne(__float_as_uint(v.y)) << 16);
}

// ---------------------------------------------------------------------------
// 0b) W -> transposed, mix-scaled bf16: WbT[l][f][dpair].
// ---------------------------------------------------------------------------
__global__ __launch_bounds__(256) void cvt_w_kernel(
    const float* __restrict__ W, const float* __restrict__ mix,
    unsigned* __restrict__ WbT)
{
    int idx = blockIdx.x * 256 + threadIdx.x;   // 0 .. L*64*128
    int f = idx & 127, dp = (idx >> 7) & 63, l = idx >> 13;
    float m = mix[l];
    float a = m * W[((size_t)l * D + 2 * dp) * D + f];
    float b = m * W[((size_t)l * D + 2 * dp + 1) * D + f];
    WbT[((size_t)l * D + f) * 64 + dp] =
        bf16rne(__float_as_uint(a)) | (bf16rne(__float_as_uint(b)) << 16);
}

// ---------------------------------------------------------------------------
// 1a) hist, grid (NCHK, L): LDS hist -> pcnt counts + chunk-local prefix.
// ---------------------------------------------------------------------------
__global__ __launch_bounds__(256) void hist_kernel(
    const int* __restrict__ edge_rows,
    unsigned short* __restrict__ pcnt,
    unsigned short* __restrict__ chunkoff)
{
    __shared__ int cnt[NB];
    __shared__ int psum[256];
    const int blk = blockIdx.x, g = blockIdx.y, tid = threadIdx.x;

    for (int i = tid; i < NB; i += 256) cnt[i] = 0;
    __syncthreads();

    const int* rows = edge_rows + (size_t)g * E + (size_t)blk * CHUNK;
    for (int i = tid; i < CHUNK; i += 256)
        atomicAdd(&cnt[rows[i] >> BSH], 1);
    __syncthreads();

    unsigned short* pc = pcnt + ((size_t)g * NCHK + blk) * NB;
    for (int i = tid; i < NB; i += 256) pc[i] = (unsigned short)cnt[i];
    __syncthreads();

    constexpr int CB = (NB + 255) / 256;   // 13
    const int base = tid * CB;
    int s = 0;
#pragma unroll
    for (int j = 0; j < CB; ++j) {
        int idx = base + j;
        if (idx < NB) s += cnt[idx];
    }
    psum[tid] = s;
    __syncthreads();
    for (int off = 1; off < 256; off <<= 1) {
        int v = (tid >= off) ? psum[tid - off] : 0;
        __syncthreads();
        psum[tid] += v;
        __syncthreads();
    }
    int carry = (tid == 0) ? 0 : psum[tid - 1];
#pragma unroll
    for (int j = 0; j < CB; ++j) {
        int idx = base + j;
        if (idx < NB) {
            int c = cnt[idx];
            cnt[idx] = carry;
            carry += c;
        }
    }
    __syncthreads();

    unsigned short* co = chunkoff + ((size_t)g * NCHK + blk) * NB;
    for (int i = tid; i < NB; i += 256) co[i] = (unsigned short)cnt[i];
}

// ---------------------------------------------------------------------------
// 1b) scatter, grid (NCHK, L): packed-u16 cursors; rank-scatter {cv, rl}
//     into LDS; coalesced copy-out.
// ---------------------------------------------------------------------------
__global__ __launch_bounds__(256) void scatter_kernel(
    const int* __restrict__ edge_rows,
    const int* __restrict__ edge_cols,
    const float* __restrict__ edge_vals,
    const unsigned short* __restrict__ chunkoff,
    unsigned* __restrict__ cvT,
    unsigned char* __restrict__ rlT)
{
    __shared__ unsigned cur[(NB + 1) / 2];
    __shared__ unsigned lcv[CHUNK];
    __shared__ unsigned char lrl[CHUNK];
    const int blk = blockIdx.x, g = blockIdx.y, tid = threadIdx.x;

    const unsigned short* co = chunkoff + ((size_t)g * NCHK + blk) * NB;
    for (int i = tid; i < (NB + 1) / 2; i += 256) {
        unsigned lo = co[2 * i];
        unsigned hi = (2 * i + 1 < NB) ? co[2 * i + 1] : 0u;
        cur[i] = lo | (hi << 16);
    }
    __syncthreads();

    const size_t eoff = (size_t)g * E + (size_t)blk * CHUNK;
    const int* rows = edge_rows + eoff;
    const int* cols = edge_cols + eoff;
    const float* vals = edge_vals + eoff;

    for (int i = tid; i < CHUNK; i += 256) {
        int r = rows[i];
        int b = r >> BSH;
        unsigned old = atomicAdd(&cur[b >> 1], (b & 1) ? 0x10000u : 1u);
        int pos = (old >> ((b & 1) * 16)) & 0xFFFFu;
        lcv[pos] = (unsigned)cols[i] | (bf16rne(__float_as_uint(vals[i])) << 16);
        lrl[pos] = (unsigned char)(r & 15);
    }
    __syncthreads();

    unsigned* cw = cvT + eoff;
    unsigned char* rw = rlT + eoff;
    for (int i = tid; i < CHUNK; i += 256) cw[i] = lcv[i];
    for (int i = tid * 4; i < CHUNK; i += 1024)
        *reinterpret_cast<uint*>(rw + i) = *reinterpret_cast<const uint*>(lrl + i);
}

// ---------------------------------------------------------------------------
// 2a) Column pass: pcnt counts -> cross-chunk offsets; totals -> bstart.
// ---------------------------------------------------------------------------
__global__ __launch_bounds__(256) void scan1_kernel(
    unsigned short* __restrict__ pcnt, int* __restrict__ bstart)
{
    const int b = blockIdx.x * 256 + threadIdx.x;
    const int g = blockIdx.y;
    if (b >= NB) return;
    unsigned run = 0;
    unsigned short* p = pcnt + (size_t)g * NCHK * NB + b;
    for (int blk = 0; blk < NCHK; ++blk) {
        unsigned v = p[(size_t)blk * NB];
        p[(size_t)blk * NB] = (unsigned short)run;
        run += v;
    }
    bstart[(size_t)g * (NB + 1) + b] = (int)run;
}

// ---------------------------------------------------------------------------
// 2b) Per-graph exclusive scan of bucket totals.
// ---------------------------------------------------------------------------
__global__ __launch_bounds__(1024) void scan2_kernel(int* __restrict__ bstart)
{
    __shared__ int sums[1024];
    int* bs = bstart + (size_t)blockIdx.x * (NB + 1);
    const int t = threadIdx.x;
    int tv[4];
    int s = 0;
#pragma unroll
    for (int i = 0; i < 4; ++i) {
        int idx = t * 4 + i;
        tv[i] = (idx < NB) ? bs[idx] : 0;
        s += tv[i];
    }
    sums[t] = s;
    __syncthreads();
    for (int off = 1; off < 1024; off <<= 1) {
        int v = (t >= off) ? sums[t - off] : 0;
        __syncthreads();
        sums[t] += v;
        __syncthreads();
    }
    int ex = (t == 0) ? 0 : sums[t - 1];
#pragma unroll
    for (int i = 0; i < 4; ++i) {
        int idx = t * 4 + i;
        if (idx < NB) { bs[idx] = ex; ex += tv[i]; }
    }
    if (t == 0) bs[NB] = E;
}

// ---------------------------------------------------------------------------
// 3) sort2 (pull payload), grid (NB, L): unchanged from R13.
// ---------------------------------------------------------------------------
__global__ __launch_bounds__(256) void sort2_kernel(
    const unsigned* __restrict__ cvT,
    const unsigned char* __restrict__ rlT,
    const unsigned short* __restrict__ pcnt,
    const unsigned short* __restrict__ chunkoff,
    const int* __restrict__ bstart,
    unsigned* __restrict__ cv,
    int* __restrict__ rowptr)
{
    __shared__ unsigned su_cv[CAP], ss_cv[CAP];
    __shared__ unsigned char su_rl[CAP];
    __shared__ int rc[17], rcur[16];
    const int b = blockIdx.x, g = blockIdx.y, tid = threadIdx.x;
    const int beg = bstart[(size_t)g * (NB + 1) + b];
    const int tot = bstart[(size_t)g * (NB + 1) + b + 1] - beg;
    const int cnt = tot < CAP ? tot : CAP;
    int* rp = rowptr + (size_t)g * (N + 1);
    if (b == 0 && tid == 0) rp[N] = E;
    if (tid < 17) rc[tid] = 0;

    if (tid < NCHK) {
        const int c = tid;
        const size_t pbase = ((size_t)g * NCHK + c) * NB + b;
        int off = pcnt[pbase];
        int nxt = (c == NCHK - 1) ? tot : (int)pcnt[pbase + NB];
        int len = nxt - off;
        const size_t wbase = (size_t)g * E + (size_t)c * CHUNK + chunkoff[pbase];
        const unsigned* cw = cvT + wbase;
        const unsigned char* rw = rlT + wbase;
        for (int i = 0; i < len; ++i) {
            int p = off + i;
            if (p < CAP) { su_cv[p] = cw[i]; su_rl[p] = rw[i]; }
        }
    }
    __syncthreads();

    for (int i = tid; i < cnt; i += 256) atomicAdd(&rc[su_rl[i] + 1], 1);
    __syncthreads();
    if (tid == 0) {
        int run = 0;
#pragma unroll
        for (int r = 1; r <= 16; ++r) { run += rc[r]; rc[r] = run; }
    }
    __syncthreads();
    if (tid < 16) {
        rcur[tid] = rc[tid];
        rp[b * 16 + tid] = beg + rc[tid];
    }
    __syncthreads();
    for (int i = tid; i < cnt; i += 256) {
        int p = atomicAdd(&rcur[su_rl[i]], 1);
        ss_cv[p] = su_cv[i];
    }
    __syncthreads();
    unsigned* cvg = cv + (size_t)g * E;
    for (int i = tid; i < cnt; i += 256) cvg[beg + i] = ss_cv[i];
}

// ---------------------------------------------------------------------------
// 4) FUSED gather + MFMA, pass q, grid (N/16): R13 structure with
//    (a) 4-slot unrolled inner groups (padding 53%->12%), (b) double-
//    buffered tile (1 barrier per l-phase). RMW out per q (q0 init+bias).
// ---------------------------------------------------------------------------
__global__ __launch_bounds__(256) void fused_kernel(
    const unsigned* __restrict__ xb,      // [4][N][16]
    const unsigned* __restrict__ cv,      // [L][E]
    const int* __restrict__ rowptr,       // [L][N+1]
    const unsigned* __restrict__ WbT,     // [L][128][64] bf16 pairs (scaled)
    const float* __restrict__ bias,
    float* __restrict__ out,
    int q)
{
    __shared__ unsigned tile[2][16][16];  // 2 KB double-buffered A tile

    const int tid = threadIdx.x;
    const int lane = tid & 63;
    const int wave = tid >> 6;
    const int sub = lane >> 4;
    const int fl = lane & 15;
    const int subbase = lane & 48;
    const int trow = wave * 4 + sub;
    const int row = blockIdx.x * 16 + trow;
    const int lrow = lane & 15, kgrp = lane >> 4;

    const unsigned* xq = xb + (size_t)q * N * 16;

    f32x4 acc[2] = {};
    int tb = 0;

    for (int l = 0; l < L; ++l) {
        const unsigned* cvg = cv + (size_t)l * E;
        const int* rp = rowptr + (size_t)l * (N + 1);
        const int beg = rp[row], end = rp[row + 1];
        float accx = 0.f, accy = 0.f;

        for (int base = beg; base < end; base += 16) {
            const int cnt = end - base;                       // uniform in sub
            unsigned cvr = (fl < cnt) ? cvg[base + fl] : 0u;  // coalesced 64B/sub
            const int ng = cnt < 13 ? ((cnt + 3) >> 2) : 4;   // 4-slot groups
            for (int kg = 0; kg < ng; ++kg) {
                const int kb = subbase + kg * 4;
                unsigned c0 = __shfl(cvr, kb + 0);
                unsigned c1 = __shfl(cvr, kb + 1);
                unsigned c2 = __shfl(cvr, kb + 2);
                unsigned c3 = __shfl(cvr, kb + 3);
                unsigned x0 = xq[(size_t)(c0 & 0xFFFFu) * 16 + fl];
                unsigned x1 = xq[(size_t)(c1 & 0xFFFFu) * 16 + fl];
                unsigned x2 = xq[(size_t)(c2 & 0xFFFFu) * 16 + fl];
                unsigned x3 = xq[(size_t)(c3 & 0xFFFFu) * 16 + fl];
                float v0 = __uint_as_float(c0 & 0xFFFF0000u);  // pad -> +0.0
                float v1 = __uint_as_float(c1 & 0xFFFF0000u);
                float v2 = __uint_as_float(c2 & 0xFFFF0000u);
                float v3 = __uint_as_float(c3 & 0xFFFF0000u);
                accx = fmaf(v0, __uint_as_float(x0 << 16), accx);
                accy = fmaf(v0, __uint_as_float(x0 & 0xFFFF0000u), accy);
                accx = fmaf(v1, __uint_as_float(x1 << 16), accx);
                accy = fmaf(v1, __uint_as_float(x1 & 0xFFFF0000u), accy);
                accx = fmaf(v2, __uint_as_float(x2 << 16), accx);
                accy = fmaf(v2, __uint_as_float(x2 & 0xFFFF0000u), accy);
                accx = fmaf(v3, __uint_as_float(x3 << 16), accx);
                accy = fmaf(v3, __uint_as_float(x3 & 0xFFFF0000u), accy);
            }
        }
        tile[tb][trow][fl] = bf16rne(__float_as_uint(accx)) |
                             (bf16rne(__float_as_uint(accy)) << 16);
        __syncthreads();   // tile[tb] writes visible; phase l-2's reads of
                           // this buffer completed before phase l-1's barrier

        U4B8 a;
        a.u = *reinterpret_cast<const uint4*>(&tile[tb][lrow][kgrp * 4]);
#pragma unroll
        for (int t = 0; t < 2; ++t) {
            const int f = wave * 32 + t * 16 + lrow;
            U4B8 bb;
            bb.u = *reinterpret_cast<const uint4*>(
                WbT + ((size_t)l * D + f) * 64 + q * 16 + kgrp * 4);
            acc[t] = __builtin_amdgcn_mfma_f32_16x16x32_bf16(a.b, bb.b, acc[t], 0, 0, 0);
        }
        tb ^= 1;   // next phase writes the other buffer
    }

#pragma unroll
    for (int t = 0; t < 2; ++t) {
        const int f = wave * 32 + t * 16 + lrow;
#pragma unroll
        for (int i = 0; i < 4; ++i) {
            int orow = blockIdx.x * 16 + kgrp * 4 + i;
            float* p = out + (size_t)orow * D + f;
            float v = acc[t][i];
            *p = (q == 0) ? v + bias[f] : *p + v;
        }
    }
}

extern "C" void kernel_launch(void* const* d_in, const int* in_sizes, int n_in,
                              void* d_out, int out_size, void* d_ws, size_t ws_size,
                              hipStream_t stream)
{
    const float* x         = (const float*)d_in[0];
    const int*   edge_rows = (const int*)d_in[1];
    const int*   edge_cols = (const int*)d_in[2];
    const float* edge_vals = (const float*)d_in[3];
    const float* W         = (const float*)d_in[4];
    const float* mix       = (const float*)d_in[5];
    const float* bias      = (const float*)d_in[6];
    float* out = (float*)d_out;

    // Workspace (~47.6 MB), layout as R13:
    // cvT [L][E] u32 (12.8M) | rlT [L][E] u8 (3.2M) | pcnt u16 (2.5M) |
    // chunkoff u16 (2.5M) | bstart (50K) | rowptr (0.8M) | cv [L][E] (12.8M) |
    // xb [4][N][16] (12.8M) | WbT (128K)
    unsigned*       cvT      = (unsigned*)d_ws;
    unsigned char*  rlT      = (unsigned char*)(cvT + (size_t)L * E);
    unsigned short* pcnt     = (unsigned short*)(rlT + (size_t)L * E);
    unsigned short* chunkoff = pcnt + (size_t)L * NCHK * NB;
    int*            bstart   = (int*)(chunkoff + (size_t)L * NCHK * NB);
    int*            rowptr   = bstart + (size_t)L * (NB + 1);
    unsigned*       cv       = (unsigned*)(rowptr + (size_t)L * (N + 1));
    unsigned*       xb       = cv + (size_t)L * E;
    unsigned*       WbT      = xb + (size_t)4 * N * 16;

    cvt_x_kernel<<<(N * 64) / 256, 256, 0, stream>>>(x, xb);
    cvt_w_kernel<<<(L * D * 64) / 256, 256, 0, stream>>>(W, mix, WbT);
    hist_kernel<<<dim3(NCHK, L), 256, 0, stream>>>(edge_rows, pcnt, chunkoff);
    scatter_kernel<<<dim3(NCHK, L), 256, 0, stream>>>(edge_rows, edge_cols,
                                                      edge_vals, chunkoff, cvT, rlT);
    scan1_kernel<<<dim3((NB + 255) / 256, L), 256, 0, stream>>>(pcnt, bstart);
    scan2_kernel<<<L, 1024, 0, stream>>>(bstart);
    sort2_kernel<<<dim3(NB, L), 256, 0, stream>>>(cvT, rlT, pcnt, chunkoff, bstart,
                                                  cv, rowptr);

    for (int q = 0; q < 4; ++q)
        fused_kernel<<<N / 16, 256, 0, stream>>>(xb, cv, rowptr, WbT, bias, out, q);
}